// Round 11
// baseline (134.777 us; speedup 1.0000x reference)
//
#include <hip/hip_runtime.h>
#include <hip/hip_bf16.h>

// MultiHeadAttention: x(16,512,256) f32; mask(1,16,512,512) bool; adj(1,16,512,512) f32;
// Wq/Wk/Wv (256,256) f32.  out = softmax(QK^T/sqrt(64) + adj, mask) @ V + x, f32.
// R10: 2-way split-K attention (each 16-row q-group = 2 waves, one per 256-key
// half; merge via LDS). VGPR 56 <= 64 -> 8 waves/SIMD; grid 2048 blocks = 32
// waves/CU (was grid-capped at 16). qkv_proj: 32-row tiles -> 768 blocks.

#define NB 16
#define NA 512
#define HID 256
#define NHEAD 8
#define DH 32
#define INV_TP 0.125f  // 1/sqrt(2*32)

typedef __attribute__((ext_vector_type(8))) short short8;   // 8 bf16 MFMA frag
typedef __attribute__((ext_vector_type(4))) float floatx4;  // MFMA acc

__device__ __forceinline__ unsigned short f2bf(float f) {
  unsigned int u = __builtin_bit_cast(unsigned int, f);
  u += 0x7fffu + ((u >> 16) & 1u);  // round-to-nearest-even
  return (unsigned short)(u >> 16);
}

__device__ __forceinline__ floatx4 mfma16(short8 a, short8 b, floatx4 c) {
  return __builtin_amdgcn_mfma_f32_16x16x32_bf16(a, b, c, 0, 0, 0);
}

__device__ __forceinline__ short8 ld8f32_bf16(const float* __restrict__ p) {
  float4 a = *(const float4*)p;
  float4 b = *(const float4*)(p + 4);
  short8 r;
  r[0] = (short)f2bf(a.x); r[1] = (short)f2bf(a.y);
  r[2] = (short)f2bf(a.z); r[3] = (short)f2bf(a.w);
  r[4] = (short)f2bf(b.x); r[5] = (short)f2bf(b.y);
  r[6] = (short)f2bf(b.z); r[7] = (short)f2bf(b.w);
  return r;
}

// Mask may arrive as 1-byte bool or normalized int32; detect from byte pattern.
__global__ void detect_mask_kernel(const unsigned int* __restrict__ m,
                                   int* __restrict__ flag) {
  __shared__ int cnt[256];
  int t = threadIdx.x, c = 0;
  for (int i = t; i < 1024; i += 256) c += (m[i] != 0u) ? 1 : 0;
  cnt[t] = c;
  __syncthreads();
  for (int s = 128; s > 0; s >>= 1) {
    if (t < s) cnt[t] += cnt[t + s];
    __syncthreads();
  }
  if (t == 0) *flag = (cnt[0] > 736) ? 1 : 0;  // 1 => bytes, 0 => int32
}

// Y[m][c] = sum_k X[m][k] * W[c][k].
// Q,K stored [b][h][n][d]; V stored TRANSPOSED [b][h][d][n].
// R10: 32-row tiles, grid (256,3) = 768 blocks (3/CU, was 1.5/CU).
__global__ __launch_bounds__(256) void qkv_proj(
    const float* __restrict__ X, const float* __restrict__ Wq,
    const float* __restrict__ Wk, const float* __restrict__ Wv,
    unsigned short* __restrict__ Y) {
  const float* W = (blockIdx.y == 0) ? Wq : (blockIdx.y == 1) ? Wk : Wv;
  unsigned short* Yo = Y + (size_t)blockIdx.y * (NB * NHEAD * NA * DH);
  const int wave = threadIdx.x >> 6, lane = threadIdx.x & 63;
  const int lr = lane & 15, lh = lane >> 4;
  const int m0 = blockIdx.x * 32;
  const int cb = wave * 64;
  const floatx4 z = {0.f, 0.f, 0.f, 0.f};
  floatx4 acc[2][4];
#pragma unroll
  for (int i = 0; i < 2; i++)
#pragma unroll
    for (int j = 0; j < 4; j++) acc[i][j] = z;

  for (int kb = 0; kb < HID; kb += 32) {
    short8 a[2], bw[4];
#pragma unroll
    for (int rt = 0; rt < 2; rt++)
      a[rt] = ld8f32_bf16(X + (size_t)(m0 + rt * 16 + lr) * HID + kb + lh * 8);
#pragma unroll
    for (int ci = 0; ci < 4; ci++)
      bw[ci] = ld8f32_bf16(W + (size_t)(cb + ci * 16 + lr) * HID + kb + lh * 8);
#pragma unroll
    for (int rt = 0; rt < 2; rt++)
#pragma unroll
      for (int ci = 0; ci < 4; ci++)
        acc[rt][ci] = mfma16(a[rt], bw[ci], acc[rt][ci]);
  }
  if (blockIdx.y == 2) {
    // V: [b][h][d][n], 4 consecutive n (rows m..m+3) packed per store.
#pragma unroll
    for (int rt = 0; rt < 2; rt++)
#pragma unroll
      for (int ci = 0; ci < 4; ci++) {
        int m = m0 + rt * 16 + lh * 4;       // rows m..m+3 (same batch: 32|512)
        int c = cb + ci * 16 + lr;
        int bb = m >> 9, n0 = m & 511, hh = c >> 5, dd = c & 31;
        ushort4 w;
        w.x = f2bf(acc[rt][ci][0]);
        w.y = f2bf(acc[rt][ci][1]);
        w.z = f2bf(acc[rt][ci][2]);
        w.w = f2bf(acc[rt][ci][3]);
        *(ushort4*)&Yo[((size_t)(bb * NHEAD + hh) * DH + dd) * NA + n0] = w;
      }
  } else {
#pragma unroll
    for (int rt = 0; rt < 2; rt++)
#pragma unroll
      for (int ci = 0; ci < 4; ci++)
#pragma unroll
        for (int r = 0; r < 4; r++) {
          int m = m0 + rt * 16 + lh * 4 + r;   // D layout: row=(l>>4)*4+reg
          int c = cb + ci * 16 + lr;           //           col=l&15
          int bb = m >> 9, n = m & 511, hh = c >> 5, dd = c & 31;
          Yo[((size_t)(bb * NHEAD + hh) * NA + n) * DH + dd] = f2bf(acc[rt][ci][r]);
        }
  }
}

// grid: (16 q-blocks of 32 rows, 8 heads, 16 batch) = 2048 blocks, 256 thr.
// Wave w: pair p=w>>1 (q-rows qb*32+p*16..+16), half hv=w&1 (keys hv*256..+256).
// Each wave: 2 key-tiles of 128 with online softmax; pairs merge via LDS.
__global__ __launch_bounds__(256, 8) void attn_fused(
    const unsigned short* __restrict__ Qw, const unsigned short* __restrict__ Kw,
    const unsigned short* __restrict__ Vtg, const float* __restrict__ X,
    const unsigned char* __restrict__ maskB, const int* __restrict__ maskI,
    const float* __restrict__ adj, const int* __restrict__ flag,
    float* __restrict__ out) {
  __shared__ float lds_o[2][2][16][33];  // [pair][half][row][col(+pad)]
  __shared__ float lds_m[2][2][16];
  __shared__ float lds_l[2][2][16];
  const int qb = blockIdx.x, h = blockIdx.y, b = blockIdx.z;
  const int t = threadIdx.x;
  const int wave = t >> 6, lane = t & 63, lr = lane & 15, lh = lane >> 4;
  const int pair = wave >> 1, hv = wave & 1;
  const int q0 = qb * 32 + pair * 16;
  const size_t bh = (size_t)(b * NHEAD + h) * NA * DH;
  const unsigned short* Kg = Kw + bh;
  const unsigned short* Vg = Vtg + bh;  // [d][n]: d*NA + n

  short8 qf = *(const short8*)&Qw[bh + (size_t)(q0 + lr) * DH + lh * 8];
  const floatx4 z = {0.f, 0.f, 0.f, 0.f};

  const int q = q0 + lr;
  const size_t rowoff = ((size_t)b * NA + q) * NA;
  const float* adjRow = adj + rowoff;
  const bool mBytes = (*flag != 0);

  float m_run = -3.0e38f, l_run = 0.f;  // state for q = q0 + lr (S^T layout)
  floatx4 o0 = z, o1 = z;               // rows q0 + lh*4 + r (C/D layout)

#pragma unroll
  for (int tile = 0; tile < 2; ++tile) {
    const int keyoff = hv * 256 + tile * 128;
    // S^T = K * Q^T: lane holds col q=lr, rows key=keyoff+kt*16+lh*4+r
    floatx4 s[8];
#pragma unroll
    for (int kt = 0; kt < 8; kt++) s[kt] = z;
#pragma unroll
    for (int kt = 0; kt < 8; kt++) {
      short8 kf = *(const short8*)&Kg[(size_t)(keyoff + kt * 16 + lr) * DH + lh * 8];
      s[kt] = mfma16(kf, qf, s[kt]);
    }

    float pmax = -3.0e38f;
#pragma unroll
    for (int kt = 0; kt < 8; kt++) {
      const int k0 = keyoff + kt * 16 + lh * 4;  // 4 consecutive keys per lane
      float4 av = *(const float4*)&adjRow[k0];
      float v0 = s[kt][0] * INV_TP + av.x;
      float v1 = s[kt][1] * INV_TP + av.y;
      float v2 = s[kt][2] * INV_TP + av.z;
      float v3 = s[kt][3] * INV_TP + av.w;
      if (mBytes) {
        uchar4 mb = *(const uchar4*)&maskB[rowoff + k0];
        if (mb.x) v0 = -1e30f;
        if (mb.y) v1 = -1e30f;
        if (mb.z) v2 = -1e30f;
        if (mb.w) v3 = -1e30f;
      } else {
        int4 mi = *(const int4*)&maskI[rowoff + k0];
        if (mi.x) v0 = -1e30f;
        if (mi.y) v1 = -1e30f;
        if (mi.z) v2 = -1e30f;
        if (mi.w) v3 = -1e30f;
      }
      s[kt][0] = v0; s[kt][1] = v1; s[kt][2] = v2; s[kt][3] = v3;
      pmax = fmaxf(pmax, fmaxf(fmaxf(v0, v1), fmaxf(v2, v3)));
    }
    // row q lives in lanes {lr, lr+16, lr+32, lr+48}
    pmax = fmaxf(pmax, __shfl_xor(pmax, 16));
    pmax = fmaxf(pmax, __shfl_xor(pmax, 32));

    const float mnew = fmaxf(m_run, pmax);
    if (tile) {  // tile 0: o/l are zero, skip rescale (shorter chain)
      const float corr = __expf(m_run - mnew);
      l_run *= corr;
#pragma unroll
      for (int r = 0; r < 4; r++) {
        float c = __shfl(corr, lh * 4 + r, 64);
        o0[r] *= c;
        o1[r] *= c;
      }
    }
    m_run = mnew;

    float sum = 0.f;
#pragma unroll
    for (int kt = 0; kt < 8; kt++) {
      float e0 = __expf(s[kt][0] - mnew);
      float e1 = __expf(s[kt][1] - mnew);
      float e2 = __expf(s[kt][2] - mnew);
      float e3 = __expf(s[kt][3] - mnew);
      s[kt][0] = e0; s[kt][1] = e1; s[kt][2] = e2; s[kt][3] = e3;
      sum += (e0 + e1) + (e2 + e3);
    }
    sum += __shfl_xor(sum, 16);
    sum += __shfl_xor(sum, 32);
    l_run += sum;

    // PV, relabeled K-dim: slot lh*8+j <-> key keyoff+32kc+(j<4 ? lh*4+j : 16+lh*4+j-4).
#pragma unroll
    for (int kc = 0; kc < 4; kc++) {
      union { short8 s8; unsigned int u[4]; } aa;
      aa.u[0] = (unsigned int)f2bf(s[2 * kc][0]) |
                ((unsigned int)f2bf(s[2 * kc][1]) << 16);
      aa.u[1] = (unsigned int)f2bf(s[2 * kc][2]) |
                ((unsigned int)f2bf(s[2 * kc][3]) << 16);
      aa.u[2] = (unsigned int)f2bf(s[2 * kc + 1][0]) |
                ((unsigned int)f2bf(s[2 * kc + 1][1]) << 16);
      aa.u[3] = (unsigned int)f2bf(s[2 * kc + 1][2]) |
                ((unsigned int)f2bf(s[2 * kc + 1][3]) << 16);
      const int kbase = keyoff + kc * 32 + lh * 4;
      union { short8 s8; uint2 u2[2]; } v0f, v1f;
      v0f.u2[0] = *(const uint2*)&Vg[(size_t)lr * NA + kbase];
      v0f.u2[1] = *(const uint2*)&Vg[(size_t)lr * NA + kbase + 16];
      v1f.u2[0] = *(const uint2*)&Vg[(size_t)(16 + lr) * NA + kbase];
      v1f.u2[1] = *(const uint2*)&Vg[(size_t)(16 + lr) * NA + kbase + 16];
      o0 = mfma16(aa.s8, v0f.s8, o0);
      o1 = mfma16(aa.s8, v1f.s8, o1);
    }
  }

  // publish partials: o rows are q0+lh*4+r (C/D), m/l are per q=q0+lr (S^T)
#pragma unroll
  for (int r = 0; r < 4; r++) {
    lds_o[pair][hv][lh * 4 + r][lr] = o0[r];
    lds_o[pair][hv][lh * 4 + r][16 + lr] = o1[r];
  }
  if (lane < 16) {
    lds_m[pair][hv][lane] = m_run;
    lds_l[pair][hv][lane] = l_run;
  }
  __syncthreads();

  // merge: wave (pair,hv) handles col-half hv of its pair's 16x32 tile.
#pragma unroll
  for (int r = 0; r < 4; r++) {
    const int row = lh * 4 + r;
    float mA = lds_m[pair][0][row], mB = lds_m[pair][1][row];
    float lA = lds_l[pair][0][row], lB = lds_l[pair][1][row];
    float ms = fmaxf(mA, mB);
    float cA = __expf(mA - ms), cB = __expf(mB - ms);
    float linv = 1.0f / (lA * cA + lB * cB);
    float oA = lds_o[pair][0][row][hv * 16 + lr];
    float oB = lds_o[pair][1][row][hv * 16 + lr];
    size_t idx = ((size_t)b * NA + (q0 + row)) * HID + h * DH + hv * 16 + lr;
    out[idx] = (oA * cA + oB * cB) * linv + X[idx];
  }
}

extern "C" void kernel_launch(void* const* d_in, const int* in_sizes, int n_in,
                              void* d_out, int out_size, void* d_ws, size_t ws_size,
                              hipStream_t stream) {
  const float* x = (const float*)d_in[0];
  const void* mask = d_in[1];
  const float* adj = (const float*)d_in[2];
  const float* Wq = (const float*)d_in[3];
  const float* Wk = (const float*)d_in[4];
  const float* Wv = (const float*)d_in[5];
  float* out = (float*)d_out;

  char* ws = (char*)d_ws;
  int* flag = (int*)ws;
  unsigned short* Qw = (unsigned short*)(ws + 4096);                 // 4 MB
  unsigned short* Kw = (unsigned short*)(ws + 4096 + 4194304);      // 4 MB
  unsigned short* Vw = (unsigned short*)(ws + 4096 + 2 * 4194304); // 4 MB (transposed)
  // requires ws_size >= ~12.6 MB

  detect_mask_kernel<<<1, 256, 0, stream>>>((const unsigned int*)mask, flag);
  qkv_proj<<<dim3(256, 3), 256, 0, stream>>>(x, Wq, Wk, Wv, Qw);
  attn_fused<<<dim3(16, NHEAD, NB), 256, 0, stream>>>(
      Qw, Kw, Vw, x, (const unsigned char*)mask, (const int*)mask, adj, flag, out);
}

// Round 13
// 113.227 us; speedup vs baseline: 1.1903x; 1.1903x over previous
//
#include <hip/hip_runtime.h>
#include <hip/hip_bf16.h>

// MultiHeadAttention: x(16,512,256) f32; mask(1,16,512,512) bool; adj(1,16,512,512) f32;
// Wq/Wk/Wv (256,256) f32.  out = softmax(QK^T/sqrt(64) + adj, mask) @ V + x, f32.
// R11: split-K attn (R10 structure, PASSED) but launch_bounds back to (256,4):
// (256,8) capped VGPR at 32 < ~60 pressure -> 125MB spill writes (the R10
// regression). Cap ~64 fits 56-60 VGPR with zero spill (R8/R9 evidence).

#define NB 16
#define NA 512
#define HID 256
#define NHEAD 8
#define DH 32
#define INV_TP 0.125f  // 1/sqrt(2*32)

typedef __attribute__((ext_vector_type(8))) short short8;   // 8 bf16 MFMA frag
typedef __attribute__((ext_vector_type(4))) float floatx4;  // MFMA acc

__device__ __forceinline__ unsigned short f2bf(float f) {
  unsigned int u = __builtin_bit_cast(unsigned int, f);
  u += 0x7fffu + ((u >> 16) & 1u);  // round-to-nearest-even
  return (unsigned short)(u >> 16);
}

__device__ __forceinline__ floatx4 mfma16(short8 a, short8 b, floatx4 c) {
  return __builtin_amdgcn_mfma_f32_16x16x32_bf16(a, b, c, 0, 0, 0);
}

__device__ __forceinline__ short8 ld8f32_bf16(const float* __restrict__ p) {
  float4 a = *(const float4*)p;
  float4 b = *(const float4*)(p + 4);
  short8 r;
  r[0] = (short)f2bf(a.x); r[1] = (short)f2bf(a.y);
  r[2] = (short)f2bf(a.z); r[3] = (short)f2bf(a.w);
  r[4] = (short)f2bf(b.x); r[5] = (short)f2bf(b.y);
  r[6] = (short)f2bf(b.z); r[7] = (short)f2bf(b.w);
  return r;
}

// Mask may arrive as 1-byte bool or normalized int32; detect from byte pattern.
__global__ void detect_mask_kernel(const unsigned int* __restrict__ m,
                                   int* __restrict__ flag) {
  __shared__ int cnt[256];
  int t = threadIdx.x, c = 0;
  for (int i = t; i < 1024; i += 256) c += (m[i] != 0u) ? 1 : 0;
  cnt[t] = c;
  __syncthreads();
  for (int s = 128; s > 0; s >>= 1) {
    if (t < s) cnt[t] += cnt[t + s];
    __syncthreads();
  }
  if (t == 0) *flag = (cnt[0] > 736) ? 1 : 0;  // 1 => bytes, 0 => int32
}

// Y[m][c] = sum_k X[m][k] * W[c][k].
// Q,K stored [b][h][n][d]; V stored TRANSPOSED [b][h][d][n].
// 32-row tiles, grid (256,3) = 768 blocks.
__global__ __launch_bounds__(256) void qkv_proj(
    const float* __restrict__ X, const float* __restrict__ Wq,
    const float* __restrict__ Wk, const float* __restrict__ Wv,
    unsigned short* __restrict__ Y) {
  const float* W = (blockIdx.y == 0) ? Wq : (blockIdx.y == 1) ? Wk : Wv;
  unsigned short* Yo = Y + (size_t)blockIdx.y * (NB * NHEAD * NA * DH);
  const int wave = threadIdx.x >> 6, lane = threadIdx.x & 63;
  const int lr = lane & 15, lh = lane >> 4;
  const int m0 = blockIdx.x * 32;
  const int cb = wave * 64;
  const floatx4 z = {0.f, 0.f, 0.f, 0.f};
  floatx4 acc[2][4];
#pragma unroll
  for (int i = 0; i < 2; i++)
#pragma unroll
    for (int j = 0; j < 4; j++) acc[i][j] = z;

  for (int kb = 0; kb < HID; kb += 32) {
    short8 a[2], bw[4];
#pragma unroll
    for (int rt = 0; rt < 2; rt++)
      a[rt] = ld8f32_bf16(X + (size_t)(m0 + rt * 16 + lr) * HID + kb + lh * 8);
#pragma unroll
    for (int ci = 0; ci < 4; ci++)
      bw[ci] = ld8f32_bf16(W + (size_t)(cb + ci * 16 + lr) * HID + kb + lh * 8);
#pragma unroll
    for (int rt = 0; rt < 2; rt++)
#pragma unroll
      for (int ci = 0; ci < 4; ci++)
        acc[rt][ci] = mfma16(a[rt], bw[ci], acc[rt][ci]);
  }
  if (blockIdx.y == 2) {
    // V: [b][h][d][n], 4 consecutive n (rows m..m+3) packed per store.
#pragma unroll
    for (int rt = 0; rt < 2; rt++)
#pragma unroll
      for (int ci = 0; ci < 4; ci++) {
        int m = m0 + rt * 16 + lh * 4;       // rows m..m+3 (same batch: 32|512)
        int c = cb + ci * 16 + lr;
        int bb = m >> 9, n0 = m & 511, hh = c >> 5, dd = c & 31;
        ushort4 w;
        w.x = f2bf(acc[rt][ci][0]);
        w.y = f2bf(acc[rt][ci][1]);
        w.z = f2bf(acc[rt][ci][2]);
        w.w = f2bf(acc[rt][ci][3]);
        *(ushort4*)&Yo[((size_t)(bb * NHEAD + hh) * DH + dd) * NA + n0] = w;
      }
  } else {
#pragma unroll
    for (int rt = 0; rt < 2; rt++)
#pragma unroll
      for (int ci = 0; ci < 4; ci++)
#pragma unroll
        for (int r = 0; r < 4; r++) {
          int m = m0 + rt * 16 + lh * 4 + r;   // D layout: row=(l>>4)*4+reg
          int c = cb + ci * 16 + lr;           //           col=l&15
          int bb = m >> 9, n = m & 511, hh = c >> 5, dd = c & 31;
          Yo[((size_t)(bb * NHEAD + hh) * NA + n) * DH + dd] = f2bf(acc[rt][ci][r]);
        }
  }
}

// grid: (16 q-blocks of 32 rows, 8 heads, 16 batch) = 2048 blocks, 256 thr.
// Wave w: pair p=w>>1 (q-rows qb*32+p*16..+16), half hv=w&1 (keys hv*256..+256).
// Each wave: 2 key-tiles of 128 with online softmax; pairs merge via LDS.
__global__ __launch_bounds__(256, 4) void attn_fused(
    const unsigned short* __restrict__ Qw, const unsigned short* __restrict__ Kw,
    const unsigned short* __restrict__ Vtg, const float* __restrict__ X,
    const unsigned char* __restrict__ maskB, const int* __restrict__ maskI,
    const float* __restrict__ adj, const int* __restrict__ flag,
    float* __restrict__ out) {
  __shared__ float lds_o[2][2][16][33];  // [pair][half][row][col(+pad)]
  __shared__ float lds_m[2][2][16];
  __shared__ float lds_l[2][2][16];
  const int qb = blockIdx.x, h = blockIdx.y, b = blockIdx.z;
  const int t = threadIdx.x;
  const int wave = t >> 6, lane = t & 63, lr = lane & 15, lh = lane >> 4;
  const int pair = wave >> 1, hv = wave & 1;
  const int q0 = qb * 32 + pair * 16;
  const size_t bh = (size_t)(b * NHEAD + h) * NA * DH;
  const unsigned short* Kg = Kw + bh;
  const unsigned short* Vg = Vtg + bh;  // [d][n]: d*NA + n

  short8 qf = *(const short8*)&Qw[bh + (size_t)(q0 + lr) * DH + lh * 8];
  const floatx4 z = {0.f, 0.f, 0.f, 0.f};

  const int q = q0 + lr;
  const size_t rowoff = ((size_t)b * NA + q) * NA;
  const float* adjRow = adj + rowoff;
  const bool mBytes = (*flag != 0);

  float m_run = -3.0e38f, l_run = 0.f;  // state for q = q0 + lr (S^T layout)
  floatx4 o0 = z, o1 = z;               // rows q0 + lh*4 + r (C/D layout)

#pragma unroll
  for (int tile = 0; tile < 2; ++tile) {
    const int keyoff = hv * 256 + tile * 128;
    // S^T = K * Q^T: lane holds col q=lr, rows key=keyoff+kt*16+lh*4+r
    floatx4 s[8];
#pragma unroll
    for (int kt = 0; kt < 8; kt++) s[kt] = z;
#pragma unroll
    for (int kt = 0; kt < 8; kt++) {
      short8 kf = *(const short8*)&Kg[(size_t)(keyoff + kt * 16 + lr) * DH + lh * 8];
      s[kt] = mfma16(kf, qf, s[kt]);
    }

    float pmax = -3.0e38f;
#pragma unroll
    for (int kt = 0; kt < 8; kt++) {
      const int k0 = keyoff + kt * 16 + lh * 4;  // 4 consecutive keys per lane
      float4 av = *(const float4*)&adjRow[k0];
      float v0 = s[kt][0] * INV_TP + av.x;
      float v1 = s[kt][1] * INV_TP + av.y;
      float v2 = s[kt][2] * INV_TP + av.z;
      float v3 = s[kt][3] * INV_TP + av.w;
      if (mBytes) {
        uchar4 mb = *(const uchar4*)&maskB[rowoff + k0];
        if (mb.x) v0 = -1e30f;
        if (mb.y) v1 = -1e30f;
        if (mb.z) v2 = -1e30f;
        if (mb.w) v3 = -1e30f;
      } else {
        int4 mi = *(const int4*)&maskI[rowoff + k0];
        if (mi.x) v0 = -1e30f;
        if (mi.y) v1 = -1e30f;
        if (mi.z) v2 = -1e30f;
        if (mi.w) v3 = -1e30f;
      }
      s[kt][0] = v0; s[kt][1] = v1; s[kt][2] = v2; s[kt][3] = v3;
      pmax = fmaxf(pmax, fmaxf(fmaxf(v0, v1), fmaxf(v2, v3)));
    }
    // row q lives in lanes {lr, lr+16, lr+32, lr+48}
    pmax = fmaxf(pmax, __shfl_xor(pmax, 16));
    pmax = fmaxf(pmax, __shfl_xor(pmax, 32));

    const float mnew = fmaxf(m_run, pmax);
    if (tile) {  // tile 0: o/l are zero, skip rescale (shorter chain)
      const float corr = __expf(m_run - mnew);
      l_run *= corr;
#pragma unroll
      for (int r = 0; r < 4; r++) {
        float c = __shfl(corr, lh * 4 + r, 64);
        o0[r] *= c;
        o1[r] *= c;
      }
    }
    m_run = mnew;

    float sum = 0.f;
#pragma unroll
    for (int kt = 0; kt < 8; kt++) {
      float e0 = __expf(s[kt][0] - mnew);
      float e1 = __expf(s[kt][1] - mnew);
      float e2 = __expf(s[kt][2] - mnew);
      float e3 = __expf(s[kt][3] - mnew);
      s[kt][0] = e0; s[kt][1] = e1; s[kt][2] = e2; s[kt][3] = e3;
      sum += (e0 + e1) + (e2 + e3);
    }
    sum += __shfl_xor(sum, 16);
    sum += __shfl_xor(sum, 32);
    l_run += sum;

    // PV, relabeled K-dim: slot lh*8+j <-> key keyoff+32kc+(j<4 ? lh*4+j : 16+lh*4+j-4).
#pragma unroll
    for (int kc = 0; kc < 4; kc++) {
      union { short8 s8; unsigned int u[4]; } aa;
      aa.u[0] = (unsigned int)f2bf(s[2 * kc][0]) |
                ((unsigned int)f2bf(s[2 * kc][1]) << 16);
      aa.u[1] = (unsigned int)f2bf(s[2 * kc][2]) |
                ((unsigned int)f2bf(s[2 * kc][3]) << 16);
      aa.u[2] = (unsigned int)f2bf(s[2 * kc + 1][0]) |
                ((unsigned int)f2bf(s[2 * kc + 1][1]) << 16);
      aa.u[3] = (unsigned int)f2bf(s[2 * kc + 1][2]) |
                ((unsigned int)f2bf(s[2 * kc + 1][3]) << 16);
      const int kbase = keyoff + kc * 32 + lh * 4;
      union { short8 s8; uint2 u2[2]; } v0f, v1f;
      v0f.u2[0] = *(const uint2*)&Vg[(size_t)lr * NA + kbase];
      v0f.u2[1] = *(const uint2*)&Vg[(size_t)lr * NA + kbase + 16];
      v1f.u2[0] = *(const uint2*)&Vg[(size_t)(16 + lr) * NA + kbase];
      v1f.u2[1] = *(const uint2*)&Vg[(size_t)(16 + lr) * NA + kbase + 16];
      o0 = mfma16(aa.s8, v0f.s8, o0);
      o1 = mfma16(aa.s8, v1f.s8, o1);
    }
  }

  // publish partials: o rows are q0+lh*4+r (C/D), m/l are per q=q0+lr (S^T)
#pragma unroll
  for (int r = 0; r < 4; r++) {
    lds_o[pair][hv][lh * 4 + r][lr] = o0[r];
    lds_o[pair][hv][lh * 4 + r][16 + lr] = o1[r];
  }
  if (lane < 16) {
    lds_m[pair][hv][lane] = m_run;
    lds_l[pair][hv][lane] = l_run;
  }
  __syncthreads();

  // merge: wave (pair,hv) handles col-half hv of its pair's 16x32 tile.
#pragma unroll
  for (int r = 0; r < 4; r++) {
    const int row = lh * 4 + r;
    float mA = lds_m[pair][0][row], mB = lds_m[pair][1][row];
    float lA = lds_l[pair][0][row], lB = lds_l[pair][1][row];
    float ms = fmaxf(mA, mB);
    float cA = __expf(mA - ms), cB = __expf(mB - ms);
    float linv = 1.0f / (lA * cA + lB * cB);
    float oA = lds_o[pair][0][row][hv * 16 + lr];
    float oB = lds_o[pair][1][row][hv * 16 + lr];
    size_t idx = ((size_t)b * NA + (q0 + row)) * HID + h * DH + hv * 16 + lr;
    out[idx] = (oA * cA + oB * cB) * linv + X[idx];
  }
}

extern "C" void kernel_launch(void* const* d_in, const int* in_sizes, int n_in,
                              void* d_out, int out_size, void* d_ws, size_t ws_size,
                              hipStream_t stream) {
  const float* x = (const float*)d_in[0];
  const void* mask = d_in[1];
  const float* adj = (const float*)d_in[2];
  const float* Wq = (const float*)d_in[3];
  const float* Wk = (const float*)d_in[4];
  const float* Wv = (const float*)d_in[5];
  float* out = (float*)d_out;

  char* ws = (char*)d_ws;
  int* flag = (int*)ws;
  unsigned short* Qw = (unsigned short*)(ws + 4096);                 // 4 MB
  unsigned short* Kw = (unsigned short*)(ws + 4096 + 4194304);      // 4 MB
  unsigned short* Vw = (unsigned short*)(ws + 4096 + 2 * 4194304); // 4 MB (transposed)
  // requires ws_size >= ~12.6 MB

  detect_mask_kernel<<<1, 256, 0, stream>>>((const unsigned int*)mask, flag);
  qkv_proj<<<dim3(256, 3), 256, 0, stream>>>(x, Wq, Wk, Wv, Qw);
  attn_fused<<<dim3(16, NHEAD, NB), 256, 0, stream>>>(
      Qw, Kw, Vw, x, (const unsigned char*)mask, (const int*)mask, adj, flag, out);
}